// Round 6
// baseline (318.029 us; speedup 1.0000x reference)
//
#include <hip/hip_runtime.h>
#include <hip/hip_bf16.h>
#include <math.h>

#define BATCH 16
#define CIN   128
#define COUT  256
#define HH    56
#define WW    56
#define HW    3136
#define NTAP  9
#define NE    (COUT*CIN*NTAP)   // 294912

typedef short short8 __attribute__((ext_vector_type(8)));
typedef float floatx4 __attribute__((ext_vector_type(4)));

// workspace layout (byte offsets, all 256-aligned)
#define WSB_CTX   0                          // fp32 [16][128]
#define WSB_ASP   8192                       // fp32 [16][16] (9 used)
#define WSB_AIN   9472                       // fp32 [16][128]
#define WSB_AOUT  17664                      // fp32 [16][256]
#define WSB_ZP    34048                      // 4096 B of zeros (conv halo source)
#define WSB_XT    38144                      // bf16 [16][3136][128]
#define WSB_DYN   (WSB_XT + BATCH*HW*CIN*2)  // bf16 [16][9][256][128]  (tap,oc,ic)

// fp32 -> bf16 RNE
static __device__ inline unsigned short f2b(float f) {
    union { float f; unsigned u; } v; v.f = f;
    unsigned r = v.u + 0x7FFF + ((v.u >> 16) & 1);
    return (unsigned short)(r >> 16);
}
static __device__ inline short8 pack8(float4 a, float4 b) {
    short8 r;
    r[0] = (short)f2b(a.x); r[1] = (short)f2b(a.y); r[2] = (short)f2b(a.z); r[3] = (short)f2b(a.w);
    r[4] = (short)f2b(b.x); r[5] = (short)f2b(b.y); r[6] = (short)f2b(b.z); r[7] = (short)f2b(b.w);
    return r;
}

// async global->LDS, 16B per lane; LDS dst = wave-uniform base + lane*16
typedef const __attribute__((address_space(1))) void* gas_ptr;
typedef __attribute__((address_space(3))) void* las_ptr;
static __device__ __forceinline__ void gl_lds16(const void* g, void* l) {
    __builtin_amdgcn_global_load_lds((gas_ptr)g, (las_ptr)l, 16, 0, 0);
}

// ---------------------------------------------------------------------------
// K1: context[b,c] = mean(x[b,c,:,:]); block 0 also zeroes the conv zero-page
__global__ void k_context(const float* __restrict__ x, float* __restrict__ ctx,
                          float* __restrict__ zp) {
    int bc = blockIdx.x;
    if (bc == 0 && threadIdx.x < 64) {
        uint4 z = {0u, 0u, 0u, 0u};
        ((uint4*)zp)[threadIdx.x] = z;   // 1024 B of zeros
    }
    const float4* p = (const float4*)(x + (size_t)bc * HW);
    float s = 0.f;
    for (int i = threadIdx.x; i < HW / 4; i += 256) { float4 v = p[i]; s += v.x + v.y + v.z + v.w; }
    for (int off = 32; off; off >>= 1) s += __shfl_down(s, off, 64);
    __shared__ float red[4];
    if ((threadIdx.x & 63) == 0) red[threadIdx.x >> 6] = s;
    __syncthreads();
    if (threadIdx.x == 0) ctx[bc] = (red[0] + red[1] + red[2] + red[3]) * (1.f / (float)HW);
}

// ---------------------------------------------------------------------------
// K2: small gates — one wave per GEMV row
__global__ void k_attn(const float* __restrict__ ctx,
                       const float* __restrict__ wsp, const float* __restrict__ bsp,
                       const float* __restrict__ win, const float* __restrict__ bin,
                       const float* __restrict__ wout, const float* __restrict__ bout,
                       float* __restrict__ asp, float* __restrict__ ain, float* __restrict__ aout) {
    int R = blockIdx.x * 4 + (threadIdx.x >> 6);
    int lane = threadIdx.x & 63;
    int b = R / 393, r = R % 393;
    const float* w; float bias; float* o;
    if (r < 9)        { w = wsp  + r * CIN;         bias = bsp[r];         o = asp  + b * 16  + r; }
    else if (r < 137) { w = win  + (r - 9) * CIN;   bias = bin[r - 9];     o = ain  + b * CIN + (r - 9); }
    else              { w = wout + (r - 137) * CIN; bias = bout[r - 137];  o = aout + b * COUT + (r - 137); }
    float2 wv = ((const float2*)w)[lane];
    float2 cv = ((const float2*)(ctx + b * CIN))[lane];
    float d = wv.x * cv.x + wv.y * cv.y;
    for (int off = 32; off; off >>= 1) d += __shfl_down(d, off, 64);
    if (lane == 0) *o = 1.f / (1.f + __expf(-(d + bias)));
}

// ---------------------------------------------------------------------------
// K3a: xt transpose/cast (LDS transpose), unchanged from round 4.
#define XT_V2_BLOCKS (BATCH * 4 * 13)   // 16 b x 4 ch-groups x 13 px-chunks
__global__ __launch_bounds__(256) void k_xt(const float* __restrict__ x,
                                            unsigned short* __restrict__ xt) {
    __shared__ unsigned short s[32 * 264];   // [c][px pad 264] 16.9 KB
    int bid = blockIdx.x;
    int b = bid / 52, rem = bid % 52;
    int chg = rem / 13, ck = rem % 13;
    int px0 = ck * 256;
    int npx = HW - px0; if (npx > 256) npx = 256;   // 256, tail chunk 64
    int tid = threadIdx.x;
    const float* xb = x + ((size_t)(b * CIN + chg * 32)) * HW + px0;
#pragma unroll
    for (int pass = 0; pass < 8; ++pass) {
        int i = pass * 256 + tid;
        int c = i >> 6, p4 = i & 63;        // wave: one channel, 64 float4 = 1KB
        int px = p4 * 4;
        if (px < npx) {
            float4 v = *(const float4*)(xb + (size_t)c * HW + px);
            unsigned short h[4] = {f2b(v.x), f2b(v.y), f2b(v.z), f2b(v.w)};
            *(uint2*)(&s[c * 264 + px]) = *(const uint2*)h;
        }
    }
    __syncthreads();
    int px = tid;
    if (px < npx) {
        unsigned short h[32];
#pragma unroll
        for (int c = 0; c < 32; ++c) h[c] = s[c * 264 + px];  // 2-way free
        uint4* dst = (uint4*)(xt + ((size_t)b * HW + px0 + px) * CIN + chg * 32);
        const uint4* q = (const uint4*)h;
        dst[0] = q[0]; dst[1] = q[1]; dst[2] = q[2]; dst[3] = q[3];
    }
}

// ---------------------------------------------------------------------------
// K3b: dyn build v5 — async gl_lds staging of wk (m97 structure).
// Mechanism being attacked: previous builds held wk's in-flight bytes in
// VGPRs; the compiler allocates lean (v2: 40 VGPR) and serializes the
// load->pack->MFMA chain into ~2-3-load vmcnt batches -> HBM-latency-bound
// at ~1 TB/s (R3 counters: everything idle). gl_lds moves the in-flight
// stream into the DMA queue (zero VGPR), 8 issues/thread per chunk.
// K chunked x4: stage 256 rows x 32 floats (32 KB) -> barrier -> ds_read/
// pack8/MFMA from LDS, acc[j] accumulates across chunks. LDS reads are
// bank-spread by pre-swizzling the GLOBAL source at 32B-pair granularity
// (h' = h ^ (row&3)); read applies the same XOR (involution). LDS 41.6 KB
// -> 3 blocks/CU; DMA drains of one block overlap compute of the others.
#define BUILD_BLOCKS 1152         // NE / 256
__global__ __launch_bounds__(256, 3) void k_build(
    const float* __restrict__ ctx, const float* __restrict__ wk,
    const float* __restrict__ bk, const float* __restrict__ base,
    const float* __restrict__ asp, const float* __restrict__ ain,
    const float* __restrict__ aout, unsigned short* __restrict__ dyn) {
    __shared__ float s_wk[256 * 32];                 // 32 KB chunk buffer
    __shared__ unsigned short s_res[9 * 530 + 16];   // [tap(pad 530)][b*32+ds]
    int bid = blockIdx.x;
    int tid = threadIdx.x;
    int wid = tid >> 6, l = tid & 63;
    int lq = l & 15, quad = l >> 4;
    int e0      = bid * 256;               // first wk row of this block
    int siteMin = e0 / 9;
    int ebase   = e0 + wid * 64;           // 4 fragments of 16 rows per wave

    // prefetch per-fragment scalars early (consumed only in the gate phase)
    float bke[4], bse[4];
#pragma unroll
    for (int j = 0; j < 4; ++j) {
        unsigned e = ebase + j * 16 + lq;
        bke[j] = bk[e]; bse[j] = base[e];
    }

    // A fragments: ctx rows = batches
    short8 afr[4];
    const float* arow = ctx + lq * CIN;
#pragma unroll
    for (int kc = 0; kc < 4; ++kc) {
        float4 v0 = *(const float4*)(arow + kc * 32 + quad * 8);
        float4 v1 = *(const float4*)(arow + kc * 32 + quad * 8 + 4);
        afr[kc] = pack8(v0, v1);
    }

    int pp = l & 7, h = pp >> 1, lo = pp & 1;   // staging piece coords

    floatx4 acc[4];
#pragma unroll
    for (int j = 0; j < 4; ++j) acc[j] = (floatx4){0.f, 0.f, 0.f, 0.f};

    for (int kc = 0; kc < 4; ++kc) {
        __syncthreads();               // chunk buffer free (prev chunk reads done)
#pragma unroll
        for (int i = 0; i < 8; ++i) {
            int row = i * 32 + wid * 8 + (l >> 3);          // u>>3
            int sp  = ((h ^ (row & 3)) << 1) | lo;          // source piece
            const float* src = wk + ((size_t)(e0 + row) << 7) + kc * 32 + sp * 4;
            gl_lds16(src, (char*)s_wk + i * 4096 + wid * 1024);
        }
        __syncthreads();               // DMA complete (vmcnt(0) before barrier)
#pragma unroll
        for (int j = 0; j < 4; ++j) {
            int r  = wid * 64 + j * 16 + lq;                // row within block
            int hs = quad ^ (r & 3);                        // same involution
            const char* pb = (const char*)s_wk + r * 128 + hs * 32;
            float4 v0 = *(const float4*)pb;
            float4 v1 = *(const float4*)(pb + 16);
            short8 bfr = pack8(v0, v1);
            acc[j] = __builtin_amdgcn_mfma_f32_16x16x32_bf16(afr[kc], bfr, acc[j], 0, 0, 0);
        }
    }

    // gates + stage results into s_res
#pragma unroll
    for (int j = 0; j < 4; ++j) {
        unsigned e = ebase + j * 16 + lq;
        unsigned site = e / 9u, tap = e - site * 9u;
        unsigned oc = site >> 7, ic = site & 127;
        unsigned ds = site - siteMin;                       // 0..29
#pragma unroll
        for (int r = 0; r < 4; ++r) {
            int bb = quad * 4 + r;
            float sg = 1.f / (1.f + __expf(-(acc[j][r] + bke[j])));
            float v = bse[j] * sg * aout[bb * COUT + oc] * ain[bb * CIN + ic] * asp[bb * 16 + tap];
            s_res[tap * 530 + bb * 32 + ds] = f2b(v);
        }
    }
    __syncthreads();
    // write-out: 144 (tap,b) runs, one per half-wave, ~58B contiguous each
    int hw_id = threadIdx.x >> 5;          // 0..7
    int hl    = threadIdx.x & 31;
#pragma unroll
    for (int it = 0; it < 18; ++it) {
        int pair = it * 8 + hw_id;         // 0..143
        int t = pair >> 4, b = pair & 15;
        int sLo = (e0 - t + 8) / 9;        // e0-t+8 >= 0
        int sHi = (e0 + 255 - t) / 9;
        int cnt = sHi - sLo + 1;           // <= 30
        if (hl < cnt) {
            unsigned short v = s_res[t * 530 + b * 32 + (sLo - siteMin) + hl];
            dyn[(size_t)b * NE + t * 32768 + sLo + hl] = v;
        }
    }
}

// ---------------------------------------------------------------------------
// K4: conv as MFMA implicit GEMM. 448 blocks, XCD-swizzled. Block: 64 oc x 8
// output rows. Staging via global_load_lds width=16.
__global__ __launch_bounds__(256, 2) void k_conv(
    const unsigned short* __restrict__ xt, const unsigned short* __restrict__ dyn,
    const float* __restrict__ bias, float* __restrict__ out,
    const unsigned short* __restrict__ zp) {
    __shared__ char s_x[640 * 64];   // 40 KiB
    __shared__ char s_a[576 * 64];   // 36 KiB
    int id  = blockIdx.x;
    int low = id & 7;
    int q   = id >> 3;
    int r   = q % 7;
    int phi = q / 7;
    int p   = phi * 8 + low;
    int oc0 = (p >> 4) * 64;
    int b   = p & 15;
    int r0  = r * 8;

    int tid = threadIdx.x;
    int wn = tid >> 6, l = tid & 63, lq = l & 15, quad = l >> 4;
    const unsigned short* xtb  = xt  + (size_t)b * HW * CIN;
    const unsigned short* dynb = dyn + (size_t)b * NE;

    int colx = wn * 16 + (l >> 2);
    int gxs  = colx - 1;
    bool gxok = (unsigned)gxs < (unsigned)WW;
    const unsigned short* zsrc = zp + l * 8;   // 16 B of zeros per lane

    int pixaddr[7];
#pragma unroll
    for (int nf = 0; nf < 7; ++nf) {
        int n = nf * 16 + lq;
        int tr = wn * 2 + n / 56, col = n % 56;
        pixaddr[nf] = (tr * 64 + col) * 64 + quad * 16;
    }

    floatx4 acc[4][7];
#pragma unroll
    for (int i = 0; i < 4; ++i)
#pragma unroll
        for (int j = 0; j < 7; ++j) acc[i][j] = (floatx4){0.f, 0.f, 0.f, 0.f};

    for (int kc = 0; kc < 4; ++kc) {
        __syncthreads();
#pragma unroll
        for (int ry = 0; ry < 10; ++ry) {
            int gy = r0 + ry - 1;
            const unsigned short* src =
                (gxok && (unsigned)gy < (unsigned)HH)
                    ? xtb + (size_t)(gy * WW + gxs) * CIN + kc * 32 + (l & 3) * 8
                    : zsrc;
            gl_lds16(src, s_x + ry * 4096 + wn * 1024);
        }
#pragma unroll
        for (int i = 0; i < 9; ++i) {
            int u = i * 256 + tid;
            int icq2 = u & 3, oc = (u >> 2) & 63, tap = u >> 8;
            gl_lds16(dynb + (size_t)(tap * COUT + oc0 + oc) * CIN + kc * 32 + icq2 * 8,
                     s_a + i * 4096 + wn * 1024);
        }
        __syncthreads();
        __builtin_amdgcn_s_setprio(1);
#pragma unroll
        for (int tap = 0; tap < 9; ++tap) {
            short8 af[4];
#pragma unroll
            for (int mf = 0; mf < 4; ++mf)
                af[mf] = *(const short8*)(s_a + (tap * 64 + mf * 16 + lq) * 64 + quad * 16);
            int toff = (tap / 3) * 4096 + (tap % 3) * 64;
#pragma unroll
            for (int nf = 0; nf < 7; ++nf) {
                short8 bf = *(const short8*)(s_x + pixaddr[nf] + toff);
#pragma unroll
                for (int mf = 0; mf < 4; ++mf)
                    acc[mf][nf] = __builtin_amdgcn_mfma_f32_16x16x32_bf16(af[mf], bf, acc[mf][nf], 0, 0, 0);
            }
        }
        __builtin_amdgcn_s_setprio(0);
    }

#pragma unroll
    for (int mf = 0; mf < 4; ++mf) {
#pragma unroll
        for (int rr = 0; rr < 4; ++rr) {
            int oc = oc0 + mf * 16 + quad * 4 + rr;
            float bs = bias[oc];
            float* ob = out + (size_t)(b * COUT + oc) * HW + (r0 + wn * 2) * 56 + lq;
#pragma unroll
            for (int nf = 0; nf < 7; ++nf)
                ob[nf * 16] = acc[mf][nf][rr] + bs;
        }
    }
}

// ---------------------------------------------------------------------------
extern "C" void kernel_launch(void* const* d_in, const int* in_sizes, int n_in,
                              void* d_out, int out_size, void* d_ws, size_t ws_size,
                              hipStream_t stream) {
    const float* x    = (const float*)d_in[0];
    const float* base = (const float*)d_in[1];
    const float* bias = (const float*)d_in[2];
    const float* wsp  = (const float*)d_in[3];
    const float* bsp  = (const float*)d_in[4];
    const float* win  = (const float*)d_in[5];
    const float* bin  = (const float*)d_in[6];
    const float* wout = (const float*)d_in[7];
    const float* bout = (const float*)d_in[8];
    const float* wk   = (const float*)d_in[9];
    const float* bk   = (const float*)d_in[10];
    float* out = (float*)d_out;
    char* ws = (char*)d_ws;

    float* ctx  = (float*)(ws + WSB_CTX);
    float* asp  = (float*)(ws + WSB_ASP);
    float* ain  = (float*)(ws + WSB_AIN);
    float* aout = (float*)(ws + WSB_AOUT);
    float* zp   = (float*)(ws + WSB_ZP);
    unsigned short* xt  = (unsigned short*)(ws + WSB_XT);
    unsigned short* dyn = (unsigned short*)(ws + WSB_DYN);

    k_context<<<BATCH * CIN, 256, 0, stream>>>(x, ctx, zp);
    k_attn<<<(BATCH * 393) / 4, 256, 0, stream>>>(ctx, wsp, bsp, win, bin, wout, bout, asp, ain, aout);
    k_xt<<<XT_V2_BLOCKS, 256, 0, stream>>>(x, xt);
    k_build<<<BUILD_BLOCKS, 256, 0, stream>>>(ctx, wk, bk, base, asp, ain, aout, dyn);
    k_conv<<<448, 256, 0, stream>>>(xt, dyn, bias, out, (const unsigned short*)zp);
}